// Round 18
// baseline (266.605 us; speedup 1.0000x reference)
//
#include <hip/hip_runtime.h>
#include <stdint.h>

typedef __attribute__((ext_vector_type(8))) __bf16 bf16x8;
typedef __attribute__((ext_vector_type(4))) float f32x4;
typedef __attribute__((ext_vector_type(8))) unsigned short ushort8;

#define T_TOK 2048
#define D_DIM 1024
#define DFF   2816
#define NEXP  8
#define NROWS 4096
#define BK    32
#define NW_ELEM (NEXP * DFF * D_DIM)
#define MAXTM2 24   // max m-tiles at BM=256

#define SWZ(r,g) ((g) ^ (((r) >> 1) & 3))

#define TL_N    0
#define TL_BASE 16
#define TL_VAL  80
#define TL_EXP  144

__device__ __forceinline__ void lds_cp16(const void* g, void* l) {
  __builtin_amdgcn_global_load_lds(
      (const __attribute__((address_space(1))) void*)g,
      (__attribute__((address_space(3))) void*)l, 16, 0, 0);
}

__device__ __forceinline__ ushort8 pack_bf16x8(float4 a, float4 b) {
  union { __bf16 h[8]; ushort8 u; } r;
  r.h[0] = (__bf16)a.x; r.h[1] = (__bf16)a.y; r.h[2] = (__bf16)a.z; r.h[3] = (__bf16)a.w;
  r.h[4] = (__bf16)b.x; r.h[5] = (__bf16)b.y; r.h[6] = (__bf16)b.z; r.h[7] = (__bf16)b.w;
  return r.u;
}

__device__ __forceinline__ unsigned short f2bf(float f) {
  union { __bf16 h; unsigned short u; } r;
  r.h = (__bf16)f;
  return r.u;
}

__device__ __forceinline__ float bf2f(unsigned short u) {
  union { uint32_t u; float f; } v; v.u = (uint32_t)u << 16;
  return v.f;
}

// m204 bijective XCD-chunk swizzle
__device__ __forceinline__ int xcd_chunk(int bid, int nwork) {
  const int q = nwork >> 3, r = nwork & 7;
  const int xcd = bid & 7;
  const int base = (xcd < r) ? xcd * (q + 1) : r * (q + 1) + (xcd - r) * q;
  return base + (bid >> 3);
}

// ---------- 1. routing + tile list (BM=256) ----------
__global__ __launch_bounds__(512) void routing_kernel(
    const int* __restrict__ ids, const float* __restrict__ w,
    int* __restrict__ cnt, int* __restrict__ off,
    int* __restrict__ tok, float* __restrict__ wgt, int* __restrict__ rowmap,
    int* __restrict__ tl2)
{
  __shared__ int s_cnt[NEXP];
  __shared__ int s_off[NEXP];
  const int lane = threadIdx.x & 63;
  const int e    = threadIdx.x >> 6;

  int total = 0;
  for (int c = 0; c < NROWS / 64; ++c) {
    int id = ids[c * 64 + lane];
    unsigned long long b = __ballot(id == e);
    total += __popcll(b);
  }
  if (lane == 0) s_cnt[e] = total;
  __syncthreads();
  if (threadIdx.x == 0) {
    int acc = 0, n2 = 0;
    for (int i = 0; i < NEXP; ++i) {
      s_off[i] = acc; off[i] = acc; cnt[i] = s_cnt[i];
      for (int j = 0; j < s_cnt[i]; j += 256) {
        tl2[TL_BASE + n2] = acc + j;
        tl2[TL_VAL  + n2] = min(256, s_cnt[i] - j);
        tl2[TL_EXP  + n2] = i;
        ++n2;
      }
      acc += s_cnt[i];
    }
    tl2[TL_N] = n2;
  }
  __syncthreads();
  int base = s_off[e];
  for (int c = 0; c < NROWS / 64; ++c) {
    int idx = c * 64 + lane;
    int id = ids[idx];
    bool m = (id == e);
    unsigned long long b = __ballot(m);
    int pos = __popcll(b & ((1ull << lane) - 1ull));
    if (m) {
      tok[base + pos] = idx >> 1;
      wgt[base + pos] = w[idx];
      rowmap[idx] = base + pos;
    }
    base += __popcll(b);
  }
}

// ---------- 2. gather x -> bf16 compacted ----------
__global__ __launch_bounds__(256) void gather_x_kernel(
    const float* __restrict__ x, const int* __restrict__ tok,
    unsigned short* __restrict__ xg)
{
  const int i = blockIdx.x;
  const int t = tok[i];
  const float4 v = ((const float4*)(x + (size_t)t * D_DIM))[threadIdx.x];
  ushort4 o;
  o.x = f2bf(v.x); o.y = f2bf(v.y); o.z = f2bf(v.z); o.w = f2bf(v.w);
  ((ushort4*)(xg + (size_t)i * D_DIM))[threadIdx.x] = o;
}

// ---------- 3. gateup GEMM BM=256: f32 weights reg-staged, 2-buffer (48KB LDS,
//             3 blocks/CU), vmcnt(2), setprio MFMA + fused dconv tail ----------
#define BM_A 256
#define BN_A 64
#define NT_A (DFF / BN_A)              // 44
#define NWORK_A (MAXTM2 * NT_A)        // 1056
#define WCD_BLKS 1024
#define NWG_A (NWORK_A + WCD_BLKS)
#define KT_A (D_DIM / BK)              // 32

__global__ __launch_bounds__(512) void moe_gateup_f32r(
    const float* __restrict__ gate_w, const float* __restrict__ up_w,
    const unsigned short* __restrict__ xg, const float* __restrict__ wgt,
    const int* __restrict__ tl2,
    unsigned short* __restrict__ hbuf,
    const float* __restrict__ down_w, unsigned short* __restrict__ dbuf)
{
  const int bid = blockIdx.x;
  const int ntm = tl2[TL_N];
  const int nwork = ntm * NT_A;
  const int tid = threadIdx.x;
  if (bid >= nwork) {
    if (bid >= NWORK_A) {
      const int c = bid - NWORK_A;
      const size_t stride = (size_t)WCD_BLKS * 512;
      for (size_t i = (size_t)c * 512 + tid; i < NW_ELEM / 8; i += stride) {
        const size_t idx = i * 8;
        float4 a = *(const float4*)(down_w + idx);
        float4 b = *(const float4*)(down_w + idx + 4);
        *(ushort8*)(dbuf + idx) = pack_bf16x8(a, b);
      }
    }
    return;
  }
  const int w = xcd_chunk(bid, nwork);
  const int tile = w / NT_A;     // A-sharers consecutive
  const int nt   = w % NT_A;
  const int row_base = tl2[TL_BASE + tile];
  const int valid    = tl2[TL_VAL  + tile];
  const int e        = tl2[TL_EXP  + tile];
  const int n0 = nt * BN_A;

  __shared__ __align__(16) unsigned short Alds[2][BM_A * BK]; // 2 x 16KB
  __shared__ __align__(16) unsigned short Bg[2][BN_A * BK];   // 2 x 4KB
  __shared__ __align__(16) unsigned short Bu[2][BN_A * BK];   // 2 x 4KB  -> 48KB

  const int lane = tid & 63;
  const int wid = tid >> 6;
  const int wm = wid >> 1, wn = wid & 1;   // 4x2 waves, wave tile 64x32
  const int lhi = lane >> 4, llo = lane & 15;

  f32x4 accg[4][2], accu[4][2];
  #pragma unroll
  for (int i = 0; i < 4; ++i)
    #pragma unroll
    for (int j = 0; j < 2; ++j) {
      accg[i][j] = (f32x4){0.f, 0.f, 0.f, 0.f};
      accu[i][j] = (f32x4){0.f, 0.f, 0.f, 0.f};
    }

  // A addressing (pre-swizzled global source, linear LDS dst)
  const int ar0 = tid >> 2, ag = tid & 3;
  const int ar1 = ar0 + 128;
  const size_t a_src0 = (size_t)(row_base + min(ar0, valid - 1)) * D_DIM + SWZ(ar0, ag) * 8;
  const size_t a_src1 = (size_t)(row_base + min(ar1, valid - 1)) * D_DIM + SWZ(ar1, ag) * 8;

  // B addressing: threads <256 handle gate, >=256 handle up.
  const int q2 = tid & 255;
  const int br = q2 >> 2, bg2 = q2 & 3;
  const float* bsrc = ((tid < 256) ? gate_w : up_w)
                    + ((size_t)e * DFF + n0 + br) * D_DIM + bg2 * 8;
  const int bws = br * BK + SWZ(br, bg2) * 8;
  unsigned short* bdst[2];
  bdst[0] = (tid < 256) ? &Bg[0][bws] : &Bu[0][bws];
  bdst[1] = (tid < 256) ? &Bg[1][bws] : &Bu[1][bws];

  // ---- prologue: A(0) DMA, B(0) pack -> buf0, B(1) -> regs ----
  {
    float4 c0 = *(const float4*)(bsrc);
    float4 c1 = *(const float4*)(bsrc + 4);
    *(ushort8*)bdst[0] = pack_bf16x8(c0, c1);
  }
  float4 pb0 = *(const float4*)(bsrc + BK);
  float4 pb1 = *(const float4*)(bsrc + BK + 4);
  lds_cp16(xg + a_src0, &Alds[0][tid * 8]);
  lds_cp16(xg + a_src1, &Alds[0][(tid + 512) * 8]);
  asm volatile("s_waitcnt vmcnt(0) lgkmcnt(0)" ::: "memory");
  __builtin_amdgcn_s_barrier();

  for (int t = 0; t < KT_A; ++t) {
    const int cur = t & 1, nxt = cur ^ 1;
    const int kn1 = (t + 1 < KT_A) ? (t + 1) * BK : 0;
    const int kn2 = (t + 2 < KT_A) ? (t + 2) * BK : 0;

    // pre-barrier: B(t+2) f32 -> regs only (no shared-state hazard)
    float4 nb0 = *(const float4*)(bsrc + kn2);
    float4 nb1 = *(const float4*)(bsrc + kn2 + 4);

    // FIFO at wait: [B(t+1)2, A(t)2, B(t+2)2] -> vmcnt(2) completes A(t),B(t+1)
    asm volatile("s_waitcnt vmcnt(2) lgkmcnt(0)" ::: "memory");
    __builtin_amdgcn_s_barrier();

    // post-barrier staging (readers of these bufs finished before the barrier)
    lds_cp16(xg + a_src0 + kn1, &Alds[nxt][tid * 8]);
    lds_cp16(xg + a_src1 + kn1, &Alds[nxt][(tid + 512) * 8]);
    *(ushort8*)bdst[nxt] = pack_bf16x8(pb0, pb1);   // B(t+1)

    // compute tile t
    bf16x8 a[4], bgf[2], buf_[2];
    #pragma unroll
    for (int mi = 0; mi < 4; ++mi) {
      int row = wm * 64 + mi * 16 + llo;
      a[mi] = *(const bf16x8*)&Alds[cur][row * BK + SWZ(row, lhi) * 8];
    }
    #pragma unroll
    for (int ni = 0; ni < 2; ++ni) {
      int row = wn * 32 + ni * 16 + llo;
      bgf[ni]  = *(const bf16x8*)&Bg[cur][row * BK + SWZ(row, lhi) * 8];
      buf_[ni] = *(const bf16x8*)&Bu[cur][row * BK + SWZ(row, lhi) * 8];
    }
    __builtin_amdgcn_s_setprio(1);
    #pragma unroll
    for (int mi = 0; mi < 4; ++mi)
      #pragma unroll
      for (int ni = 0; ni < 2; ++ni) {
        accg[mi][ni] = __builtin_amdgcn_mfma_f32_16x16x32_bf16(a[mi], bgf[ni], accg[mi][ni], 0, 0, 0);
        accu[mi][ni] = __builtin_amdgcn_mfma_f32_16x16x32_bf16(a[mi], buf_[ni], accu[mi][ni], 0, 0, 0);
      }
    __builtin_amdgcn_s_setprio(0);

    pb0 = nb0; pb1 = nb1;
  }

  // epilogue: h = silu(g)*u*w -> bf16
  #pragma unroll
  for (int mi = 0; mi < 4; ++mi) {
    #pragma unroll
    for (int r = 0; r < 4; ++r) {
      int row = wm * 64 + mi * 16 + lhi * 4 + r;
      if (row < valid) {
        int grow = row_base + row;
        float wv = wgt[grow];
        size_t base = (size_t)grow * DFF + n0 + wn * 32;
        #pragma unroll
        for (int ni = 0; ni < 2; ++ni) {
          float g = accg[mi][ni][r];
          float u = accu[mi][ni][r];
          float h = (g / (1.f + __expf(-g))) * u * wv;
          hbuf[base + ni * 16 + llo] = f2bf(h);
        }
      }
    }
  }
}

// ---------- 4. down GEMM BM=256 x BN=128, 3-buffer pipeline, bf16 ybuf ----------
#define BM_B 256
#define BN_B 128
#define NT_B (D_DIM / BN_B)     // 8
#define SLICES_B 4
#define NWT_B (NT_B * SLICES_B) // 32
#define NWG_B (MAXTM2 * NWT_B)  // 768

#define PIPE_BARRIER_VM3() do { \
    asm volatile("s_waitcnt vmcnt(3)" ::: "memory"); \
    __builtin_amdgcn_s_barrier(); \
  } while (0)

template <bool USE_YBUF>
__global__ __launch_bounds__(512) void moe_down_bf(
    const unsigned short* __restrict__ dbuf,
    const unsigned short* __restrict__ hbuf,
    const int* __restrict__ tok,
    const int* __restrict__ tl2,
    unsigned short* __restrict__ ybuf, float* __restrict__ out_atomic)
{
  constexpr int KS = DFF / SLICES_B;   // 704
  constexpr int KT = KS / BK;          // 22

  const int bid = blockIdx.x;
  const int ntm = tl2[TL_N];
  const int nwork = ntm * NWT_B;
  if (bid >= nwork) return;
  const int w = xcd_chunk(bid, nwork);
  const int tile = w / NWT_B;
  const int rr   = w % NWT_B;
  const int nt = rr & 7;
  const int sl = rr >> 3;
  const int row_base = tl2[TL_BASE + tile];
  const int valid    = tl2[TL_VAL  + tile];
  const int e        = tl2[TL_EXP  + tile];
  const int n0 = nt * BN_B;
  const int kbeg = sl * KS;

  __shared__ __align__(16) unsigned short Alds[3][BM_B * BK]; // 3 x 16KB
  __shared__ __align__(16) unsigned short Blds[3][BN_B * BK]; // 3 x 8KB

  const int tid = threadIdx.x, lane = tid & 63, wid = tid >> 6;
  const int wm = wid >> 1, wn = wid & 1;   // 4x2 waves, wave tile 64x64
  const int lhi = lane >> 4, llo = lane & 15;

  f32x4 acc[4][4];
  #pragma unroll
  for (int i = 0; i < 4; ++i)
    #pragma unroll
    for (int j = 0; j < 4; ++j) acc[i][j] = (f32x4){0.f, 0.f, 0.f, 0.f};

  const unsigned short* db = dbuf + ((size_t)e * D_DIM + n0) * DFF;

  const int ar0 = tid >> 2, ag = tid & 3;
  const int ar1 = ar0 + 128;
  const size_t a_src0 = (size_t)(row_base + min(ar0, valid - 1)) * DFF + SWZ(ar0, ag) * 8;
  const size_t a_src1 = (size_t)(row_base + min(ar1, valid - 1)) * DFF + SWZ(ar1, ag) * 8;
  const int brr = tid >> 2, bgg = tid & 3;
  const size_t b_src = (size_t)brr * DFF + SWZ(brr, bgg) * 8;

  lds_cp16(hbuf + a_src0 + kbeg, &Alds[0][tid * 8]);
  lds_cp16(hbuf + a_src1 + kbeg, &Alds[0][(tid + 512) * 8]);
  lds_cp16(db + b_src + kbeg, &Blds[0][tid * 8]);
  {
    const int k1 = kbeg + BK;
    lds_cp16(hbuf + a_src0 + k1, &Alds[1][tid * 8]);
    lds_cp16(hbuf + a_src1 + k1, &Alds[1][(tid + 512) * 8]);
    lds_cp16(db + b_src + k1, &Blds[1][tid * 8]);
  }

  int cur = 0;
  for (int t = 0; t < KT; ++t) {
    PIPE_BARRIER_VM3();

    const int nb = (cur + 2 >= 3) ? cur - 1 : cur + 2;
    const int kn = kbeg + ((t + 2 < KT) ? (t + 2) * BK : 0);
    lds_cp16(hbuf + a_src0 + kn, &Alds[nb][tid * 8]);
    lds_cp16(hbuf + a_src1 + kn, &Alds[nb][(tid + 512) * 8]);
    lds_cp16(db + b_src + kn, &Blds[nb][tid * 8]);

    bf16x8 a[4], b[4];
    #pragma unroll
    for (int mi = 0; mi < 4; ++mi) {
      int row = wm * 64 + mi * 16 + llo;
      a[mi] = *(const bf16x8*)&Alds[cur][row * BK + SWZ(row, lhi) * 8];
    }
    #pragma unroll
    for (int ni = 0; ni < 4; ++ni) {
      int row = wn * 64 + ni * 16 + llo;
      b[ni] = *(const bf16x8*)&Blds[cur][row * BK + SWZ(row, lhi) * 8];
    }
    __builtin_amdgcn_s_setprio(1);
    #pragma unroll
    for (int mi = 0; mi < 4; ++mi)
      #pragma unroll
      for (int ni = 0; ni < 4; ++ni)
        acc[mi][ni] = __builtin_amdgcn_mfma_f32_16x16x32_bf16(a[mi], b[ni], acc[mi][ni], 0, 0, 0);
    __builtin_amdgcn_s_setprio(0);

    cur = (cur + 1 >= 3) ? 0 : cur + 1;
  }

  #pragma unroll
  for (int mi = 0; mi < 4; ++mi) {
    #pragma unroll
    for (int r = 0; r < 4; ++r) {
      int row = wm * 64 + mi * 16 + lhi * 4 + r;
      if (row < valid) {
        if (USE_YBUF) {
          unsigned short* yp = ybuf + ((size_t)sl * NROWS + row_base + row) * D_DIM + n0 + wn * 64;
          #pragma unroll
          for (int ni = 0; ni < 4; ++ni) yp[ni * 16 + llo] = f2bf(acc[mi][ni][r]);
        } else {
          int tk = tok[row_base + row];
          float* op = out_atomic + (size_t)tk * D_DIM + n0 + wn * 64;
          #pragma unroll
          for (int ni = 0; ni < 4; ++ni) atomicAdd(op + ni * 16 + llo, acc[mi][ni][r]);
        }
      }
    }
  }
}

// ---------- 5. combine (bf16 partials -> f32 out) ----------
__global__ __launch_bounds__(256) void combine_kernel(
    const unsigned short* __restrict__ ybuf, const int* __restrict__ rowmap,
    float* __restrict__ out)
{
  const int t = blockIdx.x;
  const int d = threadIdx.x * 4;
  const int r0 = rowmap[t * 2], r1 = rowmap[t * 2 + 1];
  float s0 = 0.f, s1 = 0.f, s2 = 0.f, s3 = 0.f;
  #pragma unroll
  for (int sl = 0; sl < SLICES_B; ++sl) {
    ushort4 a = *(const ushort4*)(ybuf + ((size_t)sl * NROWS + r0) * D_DIM + d);
    ushort4 b = *(const ushort4*)(ybuf + ((size_t)sl * NROWS + r1) * D_DIM + d);
    s0 += bf2f(a.x) + bf2f(b.x);
    s1 += bf2f(a.y) + bf2f(b.y);
    s2 += bf2f(a.z) + bf2f(b.z);
    s3 += bf2f(a.w) + bf2f(b.w);
  }
  float4 s = {s0, s1, s2, s3};
  *(float4*)(out + (size_t)t * D_DIM + d) = s;
}

// ---------- launch ----------
extern "C" void kernel_launch(void* const* d_in, const int* in_sizes, int n_in,
                              void* d_out, int out_size, void* d_ws, size_t ws_size,
                              hipStream_t stream) {
  const float* x      = (const float*)d_in[0];
  const float* topk_w = (const float*)d_in[1];
  const float* gate_w = (const float*)d_in[2];
  const float* up_w   = (const float*)d_in[3];
  const float* down_w = (const float*)d_in[4];
  const int*   ids    = (const int*)d_in[5];
  float* out = (float*)d_out;

  char* ws = (char*)d_ws;
  int*   cnt    = (int*)(ws + 0);
  int*   off    = (int*)(ws + 32);
  int*   tok    = (int*)(ws + 64);
  float* wgt    = (float*)(ws + 64 + NROWS * 4);
  int*   rowmap = (int*)(ws + 64 + NROWS * 8);
  int*   tl2    = (int*)(ws + 50688);

  const size_t XG_OFF = 65536;
  const size_t XG_SZ  = (size_t)NROWS * D_DIM * 2;            // 8 MB
  const size_t HB_OFF = XG_OFF + XG_SZ;
  const size_t HB_SZ  = (size_t)NROWS * DFF * 2;              // 23.07 MB
  const size_t W_SZ   = (size_t)NW_ELEM * 2;                  // 46.14 MB
  const size_t DB_OFF = HB_OFF + HB_SZ;
  const size_t YB_OFF = DB_OFF + W_SZ;
  const size_t YB_SZ  = (size_t)SLICES_B * NROWS * D_DIM * 2; // 33.6 MB (bf16)

  unsigned short* xg   = (unsigned short*)(ws + XG_OFF);
  unsigned short* hbuf = (unsigned short*)(ws + HB_OFF);
  unsigned short* dbuf = (unsigned short*)(ws + DB_OFF);
  unsigned short* ybuf = (unsigned short*)(ws + YB_OFF);

  routing_kernel<<<1, 512, 0, stream>>>(ids, topk_w, cnt, off, tok, wgt, rowmap, tl2);
  gather_x_kernel<<<NROWS, 256, 0, stream>>>(x, tok, xg);
  moe_gateup_f32r<<<NWG_A, 512, 0, stream>>>(gate_w, up_w, xg, wgt, tl2, hbuf, down_w, dbuf);

  if (ws_size >= YB_OFF + YB_SZ) {
    moe_down_bf<true><<<NWG_B, 512, 0, stream>>>(dbuf, hbuf, tok, tl2, ybuf, nullptr);
    combine_kernel<<<T_TOK, 256, 0, stream>>>(ybuf, rowmap, out);
  } else {
    hipMemsetAsync(d_out, 0, (size_t)out_size * sizeof(float), stream);
    moe_down_bf<false><<<NWG_B, 512, 0, stream>>>(dbuf, hbuf, tok, tl2, nullptr, out);
  }
}

// Round 19
// 229.296 us; speedup vs baseline: 1.1627x; 1.1627x over previous
//
#include <hip/hip_runtime.h>
#include <stdint.h>

typedef __attribute__((ext_vector_type(8))) __bf16 bf16x8;
typedef __attribute__((ext_vector_type(4))) float f32x4;
typedef __attribute__((ext_vector_type(8))) unsigned short ushort8;

#define T_TOK 2048
#define D_DIM 1024
#define DFF   2816
#define NEXP  8
#define NROWS 4096
#define BK    32
#define NW_ELEM (NEXP * DFF * D_DIM)
#define MAXTM2 24   // max m-tiles at BM=256

#define SWZ(r,g) ((g) ^ (((r) >> 1) & 3))

#define TL_N    0
#define TL_BASE 16
#define TL_VAL  80
#define TL_EXP  144

__device__ __forceinline__ void lds_cp16(const void* g, void* l) {
  __builtin_amdgcn_global_load_lds(
      (const __attribute__((address_space(1))) void*)g,
      (__attribute__((address_space(3))) void*)l, 16, 0, 0);
}

__device__ __forceinline__ ushort8 pack_bf16x8(float4 a, float4 b) {
  union { __bf16 h[8]; ushort8 u; } r;
  r.h[0] = (__bf16)a.x; r.h[1] = (__bf16)a.y; r.h[2] = (__bf16)a.z; r.h[3] = (__bf16)a.w;
  r.h[4] = (__bf16)b.x; r.h[5] = (__bf16)b.y; r.h[6] = (__bf16)b.z; r.h[7] = (__bf16)b.w;
  return r.u;
}

__device__ __forceinline__ unsigned short f2bf(float f) {
  union { __bf16 h; unsigned short u; } r;
  r.h = (__bf16)f;
  return r.u;
}

__device__ __forceinline__ float bf2f(unsigned short u) {
  union { uint32_t u; float f; } v; v.u = (uint32_t)u << 16;
  return v.f;
}

// m204 bijective XCD-chunk swizzle
__device__ __forceinline__ int xcd_chunk(int bid, int nwork) {
  const int q = nwork >> 3, r = nwork & 7;
  const int xcd = bid & 7;
  const int base = (xcd < r) ? xcd * (q + 1) : r * (q + 1) + (xcd - r) * q;
  return base + (bid >> 3);
}

// ---------- 1. routing + tile list (BM=256) ----------
__global__ __launch_bounds__(512) void routing_kernel(
    const int* __restrict__ ids, const float* __restrict__ w,
    int* __restrict__ cnt, int* __restrict__ off,
    int* __restrict__ tok, float* __restrict__ wgt, int* __restrict__ rowmap,
    int* __restrict__ tl2)
{
  __shared__ int s_cnt[NEXP];
  __shared__ int s_off[NEXP];
  const int lane = threadIdx.x & 63;
  const int e    = threadIdx.x >> 6;

  int total = 0;
  for (int c = 0; c < NROWS / 64; ++c) {
    int id = ids[c * 64 + lane];
    unsigned long long b = __ballot(id == e);
    total += __popcll(b);
  }
  if (lane == 0) s_cnt[e] = total;
  __syncthreads();
  if (threadIdx.x == 0) {
    int acc = 0, n2 = 0;
    for (int i = 0; i < NEXP; ++i) {
      s_off[i] = acc; off[i] = acc; cnt[i] = s_cnt[i];
      for (int j = 0; j < s_cnt[i]; j += 256) {
        tl2[TL_BASE + n2] = acc + j;
        tl2[TL_VAL  + n2] = min(256, s_cnt[i] - j);
        tl2[TL_EXP  + n2] = i;
        ++n2;
      }
      acc += s_cnt[i];
    }
    tl2[TL_N] = n2;
  }
  __syncthreads();
  int base = s_off[e];
  for (int c = 0; c < NROWS / 64; ++c) {
    int idx = c * 64 + lane;
    int id = ids[idx];
    bool m = (id == e);
    unsigned long long b = __ballot(m);
    int pos = __popcll(b & ((1ull << lane) - 1ull));
    if (m) {
      tok[base + pos] = idx >> 1;
      wgt[base + pos] = w[idx];
      rowmap[idx] = base + pos;
    }
    base += __popcll(b);
  }
}

// ---------- 2. gather x -> bf16 compacted ----------
__global__ __launch_bounds__(256) void gather_x_kernel(
    const float* __restrict__ x, const int* __restrict__ tok,
    unsigned short* __restrict__ xg)
{
  const int i = blockIdx.x;
  const int t = tok[i];
  const float4 v = ((const float4*)(x + (size_t)t * D_DIM))[threadIdx.x];
  ushort4 o;
  o.x = f2bf(v.x); o.y = f2bf(v.y); o.z = f2bf(v.z); o.w = f2bf(v.w);
  ((ushort4*)(xg + (size_t)i * D_DIM))[threadIdx.x] = o;
}

// ---------- 3. gateup GEMM BM=256: f32 weights reg-staged in-loop (no wconv)
//             3-buffer, vmcnt(6), stage-after-barrier, setprio MFMA ----------
#define BM_A 256
#define BN_A 64
#define NT_A (DFF / BN_A)              // 44
#define NWORK_A (MAXTM2 * NT_A)        // 1056
#define WCD_BLKS 1024
#define NWG_A (NWORK_A + WCD_BLKS)
#define KT_A (D_DIM / BK)              // 32

__global__ __launch_bounds__(512) void moe_gateup_f32r(
    const float* __restrict__ gate_w, const float* __restrict__ up_w,
    const unsigned short* __restrict__ xg, const float* __restrict__ wgt,
    const int* __restrict__ tl2,
    unsigned short* __restrict__ hbuf,
    const float* __restrict__ down_w, unsigned short* __restrict__ dbuf)
{
  const int bid = blockIdx.x;
  const int ntm = tl2[TL_N];
  const int nwork = ntm * NT_A;
  const int tid = threadIdx.x;
  if (bid >= nwork) {
    if (bid >= NWORK_A) {
      const int c = bid - NWORK_A;
      const size_t stride = (size_t)WCD_BLKS * 512;
      for (size_t i = (size_t)c * 512 + tid; i < NW_ELEM / 8; i += stride) {
        const size_t idx = i * 8;
        float4 a = *(const float4*)(down_w + idx);
        float4 b = *(const float4*)(down_w + idx + 4);
        *(ushort8*)(dbuf + idx) = pack_bf16x8(a, b);
      }
    }
    return;
  }
  const int w = xcd_chunk(bid, nwork);
  const int tile = w / NT_A;     // A-sharers consecutive
  const int nt   = w % NT_A;
  const int row_base = tl2[TL_BASE + tile];
  const int valid    = tl2[TL_VAL  + tile];
  const int e        = tl2[TL_EXP  + tile];
  const int n0 = nt * BN_A;

  __shared__ __align__(16) unsigned short Alds[3][BM_A * BK]; // 3 x 16KB
  __shared__ __align__(16) unsigned short Bg[3][BN_A * BK];   // 3 x 4KB
  __shared__ __align__(16) unsigned short Bu[3][BN_A * BK];   // 3 x 4KB  -> 72KB

  const int lane = tid & 63;
  const int wid = tid >> 6;
  const int wm = wid >> 1, wn = wid & 1;   // 4x2 waves, wave tile 64x32
  const int lhi = lane >> 4, llo = lane & 15;

  f32x4 accg[4][2], accu[4][2];
  #pragma unroll
  for (int i = 0; i < 4; ++i)
    #pragma unroll
    for (int j = 0; j < 2; ++j) {
      accg[i][j] = (f32x4){0.f, 0.f, 0.f, 0.f};
      accu[i][j] = (f32x4){0.f, 0.f, 0.f, 0.f};
    }

  // A addressing (pre-swizzled global source, linear LDS dst)
  const int ar0 = tid >> 2, ag = tid & 3;
  const int ar1 = ar0 + 128;
  const size_t a_src0 = (size_t)(row_base + min(ar0, valid - 1)) * D_DIM + SWZ(ar0, ag) * 8;
  const size_t a_src1 = (size_t)(row_base + min(ar1, valid - 1)) * D_DIM + SWZ(ar1, ag) * 8;

  // B addressing: threads <256 handle gate, >=256 handle up.
  const int q2 = tid & 255;
  const int br = q2 >> 2, bg2 = q2 & 3;
  const float* bsrc = ((tid < 256) ? gate_w : up_w)
                    + ((size_t)e * DFF + n0 + br) * D_DIM + bg2 * 8;
  const int bws = br * BK + SWZ(br, bg2) * 8;
  unsigned short* bdst[3];
  bdst[0] = (tid < 256) ? &Bg[0][bws] : &Bu[0][bws];
  bdst[1] = (tid < 256) ? &Bg[1][bws] : &Bu[1][bws];
  bdst[2] = (tid < 256) ? &Bg[2][bws] : &Bu[2][bws];

  // ---- prologue ----
  {
    float4 c0 = *(const float4*)(bsrc);
    float4 c1 = *(const float4*)(bsrc + 4);
    *(ushort8*)bdst[0] = pack_bf16x8(c0, c1);      // B(0) -> buf0
  }
  float4 pb0 = *(const float4*)(bsrc + BK);        // B(1) -> pipeline regs
  float4 pb1 = *(const float4*)(bsrc + BK + 4);
  lds_cp16(xg + a_src0, &Alds[0][tid * 8]);        // A(0), A(1) DMA
  lds_cp16(xg + a_src1, &Alds[0][(tid + 512) * 8]);
  lds_cp16(xg + a_src0 + BK, &Alds[1][tid * 8]);
  lds_cp16(xg + a_src1 + BK, &Alds[1][(tid + 512) * 8]);
  asm volatile("s_waitcnt vmcnt(0) lgkmcnt(0)" ::: "memory");
  __builtin_amdgcn_s_barrier();

  int cur = 0;
  for (int t = 0; t < KT_A; ++t) {
    const int nxt = (cur + 1 >= 3) ? cur - 2 : cur + 1;
    const int nb  = (cur + 2 >= 3) ? cur - 1 : cur + 2;
    const int kn2 = (t + 2 < KT_A) ? (t + 2) * BK : 0;

    // pre-barrier: B(t+2) f32 -> regs only (no shared-state hazard)
    float4 nb0 = *(const float4*)(bsrc + kn2);
    float4 nb1 = *(const float4*)(bsrc + kn2 + 4);

    // A(t) landed: 6 younger vmem ops (B(t+1) 2, A(t+1) 2, B(t+2) 2).
    asm volatile("s_waitcnt vmcnt(6) lgkmcnt(0)" ::: "memory");
    __builtin_amdgcn_s_barrier();

    // post-barrier staging (readers of these bufs finished before the barrier)
    lds_cp16(xg + a_src0 + kn2, &Alds[nb][tid * 8]);
    lds_cp16(xg + a_src1 + kn2, &Alds[nb][(tid + 512) * 8]);
    *(ushort8*)bdst[nxt] = pack_bf16x8(pb0, pb1);   // B(t+1) -> buf (t+1)%3

    // compute tile t
    bf16x8 a[4], bgf[2], buf_[2];
    #pragma unroll
    for (int mi = 0; mi < 4; ++mi) {
      int row = wm * 64 + mi * 16 + llo;
      a[mi] = *(const bf16x8*)&Alds[cur][row * BK + SWZ(row, lhi) * 8];
    }
    #pragma unroll
    for (int ni = 0; ni < 2; ++ni) {
      int row = wn * 32 + ni * 16 + llo;
      bgf[ni]  = *(const bf16x8*)&Bg[cur][row * BK + SWZ(row, lhi) * 8];
      buf_[ni] = *(const bf16x8*)&Bu[cur][row * BK + SWZ(row, lhi) * 8];
    }
    __builtin_amdgcn_s_setprio(1);
    #pragma unroll
    for (int mi = 0; mi < 4; ++mi)
      #pragma unroll
      for (int ni = 0; ni < 2; ++ni) {
        accg[mi][ni] = __builtin_amdgcn_mfma_f32_16x16x32_bf16(a[mi], bgf[ni], accg[mi][ni], 0, 0, 0);
        accu[mi][ni] = __builtin_amdgcn_mfma_f32_16x16x32_bf16(a[mi], buf_[ni], accu[mi][ni], 0, 0, 0);
      }
    __builtin_amdgcn_s_setprio(0);

    pb0 = nb0; pb1 = nb1;
    cur = (cur + 1 >= 3) ? 0 : cur + 1;
  }

  // epilogue: h = silu(g)*u*w -> bf16
  #pragma unroll
  for (int mi = 0; mi < 4; ++mi) {
    #pragma unroll
    for (int r = 0; r < 4; ++r) {
      int row = wm * 64 + mi * 16 + lhi * 4 + r;
      if (row < valid) {
        int grow = row_base + row;
        float wv = wgt[grow];
        size_t base = (size_t)grow * DFF + n0 + wn * 32;
        #pragma unroll
        for (int ni = 0; ni < 2; ++ni) {
          float g = accg[mi][ni][r];
          float u = accu[mi][ni][r];
          float h = (g / (1.f + __expf(-g))) * u * wv;
          hbuf[base + ni * 16 + llo] = f2bf(h);
        }
      }
    }
  }
}

// ---------- 4. down GEMM BM=256 x BN=128, 3-buffer pipeline, bf16 ybuf ----------
#define BM_B 256
#define BN_B 128
#define NT_B (D_DIM / BN_B)     // 8
#define SLICES_B 4
#define NWT_B (NT_B * SLICES_B) // 32
#define NWG_B (MAXTM2 * NWT_B)  // 768

#define PIPE_BARRIER_VM3() do { \
    asm volatile("s_waitcnt vmcnt(3)" ::: "memory"); \
    __builtin_amdgcn_s_barrier(); \
  } while (0)

template <bool USE_YBUF>
__global__ __launch_bounds__(512) void moe_down_bf(
    const unsigned short* __restrict__ dbuf,
    const unsigned short* __restrict__ hbuf,
    const int* __restrict__ tok,
    const int* __restrict__ tl2,
    unsigned short* __restrict__ ybuf, float* __restrict__ out_atomic)
{
  constexpr int KS = DFF / SLICES_B;   // 704
  constexpr int KT = KS / BK;          // 22

  const int bid = blockIdx.x;
  const int ntm = tl2[TL_N];
  const int nwork = ntm * NWT_B;
  if (bid >= nwork) return;
  const int w = xcd_chunk(bid, nwork);
  const int tile = w / NWT_B;
  const int rr   = w % NWT_B;
  const int nt = rr & 7;
  const int sl = rr >> 3;
  const int row_base = tl2[TL_BASE + tile];
  const int valid    = tl2[TL_VAL  + tile];
  const int e        = tl2[TL_EXP  + tile];
  const int n0 = nt * BN_B;
  const int kbeg = sl * KS;

  __shared__ __align__(16) unsigned short Alds[3][BM_B * BK]; // 3 x 16KB
  __shared__ __align__(16) unsigned short Blds[3][BN_B * BK]; // 3 x 8KB

  const int tid = threadIdx.x, lane = tid & 63, wid = tid >> 6;
  const int wm = wid >> 1, wn = wid & 1;   // 4x2 waves, wave tile 64x64
  const int lhi = lane >> 4, llo = lane & 15;

  f32x4 acc[4][4];
  #pragma unroll
  for (int i = 0; i < 4; ++i)
    #pragma unroll
    for (int j = 0; j < 4; ++j) acc[i][j] = (f32x4){0.f, 0.f, 0.f, 0.f};

  const unsigned short* db = dbuf + ((size_t)e * D_DIM + n0) * DFF;

  const int ar0 = tid >> 2, ag = tid & 3;
  const int ar1 = ar0 + 128;
  const size_t a_src0 = (size_t)(row_base + min(ar0, valid - 1)) * DFF + SWZ(ar0, ag) * 8;
  const size_t a_src1 = (size_t)(row_base + min(ar1, valid - 1)) * DFF + SWZ(ar1, ag) * 8;
  const int brr = tid >> 2, bgg = tid & 3;
  const size_t b_src = (size_t)brr * DFF + SWZ(brr, bgg) * 8;

  lds_cp16(hbuf + a_src0 + kbeg, &Alds[0][tid * 8]);
  lds_cp16(hbuf + a_src1 + kbeg, &Alds[0][(tid + 512) * 8]);
  lds_cp16(db + b_src + kbeg, &Blds[0][tid * 8]);
  {
    const int k1 = kbeg + BK;
    lds_cp16(hbuf + a_src0 + k1, &Alds[1][tid * 8]);
    lds_cp16(hbuf + a_src1 + k1, &Alds[1][(tid + 512) * 8]);
    lds_cp16(db + b_src + k1, &Blds[1][tid * 8]);
  }

  int cur = 0;
  for (int t = 0; t < KT; ++t) {
    PIPE_BARRIER_VM3();

    const int nb = (cur + 2 >= 3) ? cur - 1 : cur + 2;
    const int kn = kbeg + ((t + 2 < KT) ? (t + 2) * BK : 0);
    lds_cp16(hbuf + a_src0 + kn, &Alds[nb][tid * 8]);
    lds_cp16(hbuf + a_src1 + kn, &Alds[nb][(tid + 512) * 8]);
    lds_cp16(db + b_src + kn, &Blds[nb][tid * 8]);

    bf16x8 a[4], b[4];
    #pragma unroll
    for (int mi = 0; mi < 4; ++mi) {
      int row = wm * 64 + mi * 16 + llo;
      a[mi] = *(const bf16x8*)&Alds[cur][row * BK + SWZ(row, lhi) * 8];
    }
    #pragma unroll
    for (int ni = 0; ni < 4; ++ni) {
      int row = wn * 64 + ni * 16 + llo;
      b[ni] = *(const bf16x8*)&Blds[cur][row * BK + SWZ(row, lhi) * 8];
    }
    __builtin_amdgcn_s_setprio(1);
    #pragma unroll
    for (int mi = 0; mi < 4; ++mi)
      #pragma unroll
      for (int ni = 0; ni < 4; ++ni)
        acc[mi][ni] = __builtin_amdgcn_mfma_f32_16x16x32_bf16(a[mi], b[ni], acc[mi][ni], 0, 0, 0);
    __builtin_amdgcn_s_setprio(0);

    cur = (cur + 1 >= 3) ? 0 : cur + 1;
  }

  #pragma unroll
  for (int mi = 0; mi < 4; ++mi) {
    #pragma unroll
    for (int r = 0; r < 4; ++r) {
      int row = wm * 64 + mi * 16 + lhi * 4 + r;
      if (row < valid) {
        if (USE_YBUF) {
          unsigned short* yp = ybuf + ((size_t)sl * NROWS + row_base + row) * D_DIM + n0 + wn * 64;
          #pragma unroll
          for (int ni = 0; ni < 4; ++ni) yp[ni * 16 + llo] = f2bf(acc[mi][ni][r]);
        } else {
          int tk = tok[row_base + row];
          float* op = out_atomic + (size_t)tk * D_DIM + n0 + wn * 64;
          #pragma unroll
          for (int ni = 0; ni < 4; ++ni) atomicAdd(op + ni * 16 + llo, acc[mi][ni][r]);
        }
      }
    }
  }
}

// ---------- 5. combine (bf16 partials -> f32 out) ----------
__global__ __launch_bounds__(256) void combine_kernel(
    const unsigned short* __restrict__ ybuf, const int* __restrict__ rowmap,
    float* __restrict__ out)
{
  const int t = blockIdx.x;
  const int d = threadIdx.x * 4;
  const int r0 = rowmap[t * 2], r1 = rowmap[t * 2 + 1];
  float s0 = 0.f, s1 = 0.f, s2 = 0.f, s3 = 0.f;
  #pragma unroll
  for (int sl = 0; sl < SLICES_B; ++sl) {
    ushort4 a = *(const ushort4*)(ybuf + ((size_t)sl * NROWS + r0) * D_DIM + d);
    ushort4 b = *(const ushort4*)(ybuf + ((size_t)sl * NROWS + r1) * D_DIM + d);
    s0 += bf2f(a.x) + bf2f(b.x);
    s1 += bf2f(a.y) + bf2f(b.y);
    s2 += bf2f(a.z) + bf2f(b.z);
    s3 += bf2f(a.w) + bf2f(b.w);
  }
  float4 s = {s0, s1, s2, s3};
  *(float4*)(out + (size_t)t * D_DIM + d) = s;
}

// ---------- launch ----------
extern "C" void kernel_launch(void* const* d_in, const int* in_sizes, int n_in,
                              void* d_out, int out_size, void* d_ws, size_t ws_size,
                              hipStream_t stream) {
  const float* x      = (const float*)d_in[0];
  const float* topk_w = (const float*)d_in[1];
  const float* gate_w = (const float*)d_in[2];
  const float* up_w   = (const float*)d_in[3];
  const float* down_w = (const float*)d_in[4];
  const int*   ids    = (const int*)d_in[5];
  float* out = (float*)d_out;

  char* ws = (char*)d_ws;
  int*   cnt    = (int*)(ws + 0);
  int*   off    = (int*)(ws + 32);
  int*   tok    = (int*)(ws + 64);
  float* wgt    = (float*)(ws + 64 + NROWS * 4);
  int*   rowmap = (int*)(ws + 64 + NROWS * 8);
  int*   tl2    = (int*)(ws + 50688);

  const size_t XG_OFF = 65536;
  const size_t XG_SZ  = (size_t)NROWS * D_DIM * 2;            // 8 MB
  const size_t HB_OFF = XG_OFF + XG_SZ;
  const size_t HB_SZ  = (size_t)NROWS * DFF * 2;              // 23.07 MB
  const size_t W_SZ   = (size_t)NW_ELEM * 2;                  // 46.14 MB
  const size_t DB_OFF = HB_OFF + HB_SZ;
  const size_t YB_OFF = DB_OFF + W_SZ;
  const size_t YB_SZ  = (size_t)SLICES_B * NROWS * D_DIM * 2; // 33.6 MB (bf16)

  unsigned short* xg   = (unsigned short*)(ws + XG_OFF);
  unsigned short* hbuf = (unsigned short*)(ws + HB_OFF);
  unsigned short* dbuf = (unsigned short*)(ws + DB_OFF);
  unsigned short* ybuf = (unsigned short*)(ws + YB_OFF);

  routing_kernel<<<1, 512, 0, stream>>>(ids, topk_w, cnt, off, tok, wgt, rowmap, tl2);
  gather_x_kernel<<<NROWS, 256, 0, stream>>>(x, tok, xg);
  moe_gateup_f32r<<<NWG_A, 512, 0, stream>>>(gate_w, up_w, xg, wgt, tl2, hbuf, down_w, dbuf);

  if (ws_size >= YB_OFF + YB_SZ) {
    moe_down_bf<true><<<NWG_B, 512, 0, stream>>>(dbuf, hbuf, tok, tl2, ybuf, nullptr);
    combine_kernel<<<T_TOK, 256, 0, stream>>>(ybuf, rowmap, out);
  } else {
    hipMemsetAsync(d_out, 0, (size_t)out_size * sizeof(float), stream);
    moe_down_bf<false><<<NWG_B, 512, 0, stream>>>(dbuf, hbuf, tok, tl2, nullptr, out);
  }
}

// Round 20
// 220.505 us; speedup vs baseline: 1.2091x; 1.0399x over previous
//
#include <hip/hip_runtime.h>
#include <stdint.h>

typedef __attribute__((ext_vector_type(8))) __bf16 bf16x8;
typedef __attribute__((ext_vector_type(4))) float f32x4;
typedef __attribute__((ext_vector_type(8))) unsigned short ushort8;

#define T_TOK 2048
#define D_DIM 1024
#define DFF   2816
#define NEXP  8
#define NROWS 4096
#define BK    32
#define MAXTM2 24   // max m-tiles at BM=256

#define SWZ(r,g) ((g) ^ (((r) >> 1) & 3))

#define TL_N    0
#define TL_BASE 16
#define TL_VAL  80
#define TL_EXP  144

__device__ __forceinline__ void lds_cp16(const void* g, void* l) {
  __builtin_amdgcn_global_load_lds(
      (const __attribute__((address_space(1))) void*)g,
      (__attribute__((address_space(3))) void*)l, 16, 0, 0);
}

__device__ __forceinline__ ushort8 pack_bf16x8(float4 a, float4 b) {
  union { __bf16 h[8]; ushort8 u; } r;
  r.h[0] = (__bf16)a.x; r.h[1] = (__bf16)a.y; r.h[2] = (__bf16)a.z; r.h[3] = (__bf16)a.w;
  r.h[4] = (__bf16)b.x; r.h[5] = (__bf16)b.y; r.h[6] = (__bf16)b.z; r.h[7] = (__bf16)b.w;
  return r.u;
}

__device__ __forceinline__ unsigned short f2bf(float f) {
  union { __bf16 h; unsigned short u; } r;
  r.h = (__bf16)f;
  return r.u;
}

__device__ __forceinline__ float bf2f(unsigned short u) {
  union { uint32_t u; float f; } v; v.u = (uint32_t)u << 16;
  return v.f;
}

// m204 bijective XCD-chunk swizzle
__device__ __forceinline__ int xcd_chunk(int bid, int nwork) {
  const int q = nwork >> 3, r = nwork & 7;
  const int xcd = bid & 7;
  const int base = (xcd < r) ? xcd * (q + 1) : r * (q + 1) + (xcd - r) * q;
  return base + (bid >> 3);
}

// ---------- 1. routing + tile list (BM=256) ----------
__global__ __launch_bounds__(512) void routing_kernel(
    const int* __restrict__ ids, const float* __restrict__ w,
    int* __restrict__ cnt, int* __restrict__ off,
    int* __restrict__ tok, float* __restrict__ wgt, int* __restrict__ rowmap,
    int* __restrict__ tl2)
{
  __shared__ int s_cnt[NEXP];
  __shared__ int s_off[NEXP];
  const int lane = threadIdx.x & 63;
  const int e    = threadIdx.x >> 6;

  int total = 0;
  for (int c = 0; c < NROWS / 64; ++c) {
    int id = ids[c * 64 + lane];
    unsigned long long b = __ballot(id == e);
    total += __popcll(b);
  }
  if (lane == 0) s_cnt[e] = total;
  __syncthreads();
  if (threadIdx.x == 0) {
    int acc = 0, n2 = 0;
    for (int i = 0; i < NEXP; ++i) {
      s_off[i] = acc; off[i] = acc; cnt[i] = s_cnt[i];
      for (int j = 0; j < s_cnt[i]; j += 256) {
        tl2[TL_BASE + n2] = acc + j;
        tl2[TL_VAL  + n2] = min(256, s_cnt[i] - j);
        tl2[TL_EXP  + n2] = i;
        ++n2;
      }
      acc += s_cnt[i];
    }
    tl2[TL_N] = n2;
  }
  __syncthreads();
  int base = s_off[e];
  for (int c = 0; c < NROWS / 64; ++c) {
    int idx = c * 64 + lane;
    int id = ids[idx];
    bool m = (id == e);
    unsigned long long b = __ballot(m);
    int pos = __popcll(b & ((1ull << lane) - 1ull));
    if (m) {
      tok[base + pos] = idx >> 1;
      wgt[base + pos] = w[idx];
      rowmap[idx] = base + pos;
    }
    base += __popcll(b);
  }
}

// ---------- 2. gather x -> bf16 compacted ----------
__global__ __launch_bounds__(256) void gather_x_kernel(
    const float* __restrict__ x, const int* __restrict__ tok,
    unsigned short* __restrict__ xg)
{
  const int i = blockIdx.x;
  const int t = tok[i];
  const float4 v = ((const float4*)(x + (size_t)t * D_DIM))[threadIdx.x];
  ushort4 o;
  o.x = f2bf(v.x); o.y = f2bf(v.y); o.z = f2bf(v.z); o.w = f2bf(v.w);
  ((ushort4*)(xg + (size_t)i * D_DIM))[threadIdx.x] = o;
}

// ---------- 3. gateup GEMM BM=256: f32 weights reg-staged in-loop
//             3-buffer, vmcnt(6), stage-after-barrier, setprio MFMA ----------
#define BM_A 256
#define BN_A 64
#define NT_A (DFF / BN_A)              // 44
#define NWG_A (MAXTM2 * NT_A)          // 1056
#define KT_A (D_DIM / BK)              // 32

__global__ __launch_bounds__(512) void moe_gateup_f32r(
    const float* __restrict__ gate_w, const float* __restrict__ up_w,
    const unsigned short* __restrict__ xg, const float* __restrict__ wgt,
    const int* __restrict__ tl2,
    unsigned short* __restrict__ hbuf)
{
  const int bid = blockIdx.x;
  const int ntm = tl2[TL_N];
  const int nwork = ntm * NT_A;
  const int tid = threadIdx.x;
  if (bid >= nwork) return;
  const int w = xcd_chunk(bid, nwork);
  const int tile = w / NT_A;     // A-sharers consecutive
  const int nt   = w % NT_A;
  const int row_base = tl2[TL_BASE + tile];
  const int valid    = tl2[TL_VAL  + tile];
  const int e        = tl2[TL_EXP  + tile];
  const int n0 = nt * BN_A;

  __shared__ __align__(16) unsigned short Alds[3][BM_A * BK]; // 3 x 16KB
  __shared__ __align__(16) unsigned short Bg[3][BN_A * BK];   // 3 x 4KB
  __shared__ __align__(16) unsigned short Bu[3][BN_A * BK];   // 3 x 4KB  -> 72KB

  const int lane = tid & 63;
  const int wid = tid >> 6;
  const int wm = wid >> 1, wn = wid & 1;   // 4x2 waves, wave tile 64x32
  const int lhi = lane >> 4, llo = lane & 15;

  f32x4 accg[4][2], accu[4][2];
  #pragma unroll
  for (int i = 0; i < 4; ++i)
    #pragma unroll
    for (int j = 0; j < 2; ++j) {
      accg[i][j] = (f32x4){0.f, 0.f, 0.f, 0.f};
      accu[i][j] = (f32x4){0.f, 0.f, 0.f, 0.f};
    }

  const int ar0 = tid >> 2, ag = tid & 3;
  const int ar1 = ar0 + 128;
  const size_t a_src0 = (size_t)(row_base + min(ar0, valid - 1)) * D_DIM + SWZ(ar0, ag) * 8;
  const size_t a_src1 = (size_t)(row_base + min(ar1, valid - 1)) * D_DIM + SWZ(ar1, ag) * 8;

  const int q2 = tid & 255;
  const int br = q2 >> 2, bg2 = q2 & 3;
  const float* bsrc = ((tid < 256) ? gate_w : up_w)
                    + ((size_t)e * DFF + n0 + br) * D_DIM + bg2 * 8;
  const int bws = br * BK + SWZ(br, bg2) * 8;
  unsigned short* bdst[3];
  bdst[0] = (tid < 256) ? &Bg[0][bws] : &Bu[0][bws];
  bdst[1] = (tid < 256) ? &Bg[1][bws] : &Bu[1][bws];
  bdst[2] = (tid < 256) ? &Bg[2][bws] : &Bu[2][bws];

  // ---- prologue ----
  {
    float4 c0 = *(const float4*)(bsrc);
    float4 c1 = *(const float4*)(bsrc + 4);
    *(ushort8*)bdst[0] = pack_bf16x8(c0, c1);      // B(0) -> buf0
  }
  float4 pb0 = *(const float4*)(bsrc + BK);        // B(1) -> pipeline regs
  float4 pb1 = *(const float4*)(bsrc + BK + 4);
  lds_cp16(xg + a_src0, &Alds[0][tid * 8]);        // A(0), A(1) DMA
  lds_cp16(xg + a_src1, &Alds[0][(tid + 512) * 8]);
  lds_cp16(xg + a_src0 + BK, &Alds[1][tid * 8]);
  lds_cp16(xg + a_src1 + BK, &Alds[1][(tid + 512) * 8]);
  asm volatile("s_waitcnt vmcnt(0) lgkmcnt(0)" ::: "memory");
  __builtin_amdgcn_s_barrier();

  int cur = 0;
  for (int t = 0; t < KT_A; ++t) {
    const int nxt = (cur + 1 >= 3) ? cur - 2 : cur + 1;
    const int nb  = (cur + 2 >= 3) ? cur - 1 : cur + 2;
    const int kn2 = (t + 2 < KT_A) ? (t + 2) * BK : 0;

    // pre-barrier: B(t+2) f32 -> regs only (no shared-state hazard)
    float4 nb0 = *(const float4*)(bsrc + kn2);
    float4 nb1 = *(const float4*)(bsrc + kn2 + 4);

    // A(t) landed: 6 younger vmem ops (B(t+1) 2, A(t+1) 2, B(t+2) 2).
    asm volatile("s_waitcnt vmcnt(6) lgkmcnt(0)" ::: "memory");
    __builtin_amdgcn_s_barrier();

    // post-barrier staging (readers of these bufs finished before the barrier)
    lds_cp16(xg + a_src0 + kn2, &Alds[nb][tid * 8]);
    lds_cp16(xg + a_src1 + kn2, &Alds[nb][(tid + 512) * 8]);
    *(ushort8*)bdst[nxt] = pack_bf16x8(pb0, pb1);   // B(t+1) -> buf (t+1)%3

    // compute tile t
    bf16x8 a[4], bgf[2], buf_[2];
    #pragma unroll
    for (int mi = 0; mi < 4; ++mi) {
      int row = wm * 64 + mi * 16 + llo;
      a[mi] = *(const bf16x8*)&Alds[cur][row * BK + SWZ(row, lhi) * 8];
    }
    #pragma unroll
    for (int ni = 0; ni < 2; ++ni) {
      int row = wn * 32 + ni * 16 + llo;
      bgf[ni]  = *(const bf16x8*)&Bg[cur][row * BK + SWZ(row, lhi) * 8];
      buf_[ni] = *(const bf16x8*)&Bu[cur][row * BK + SWZ(row, lhi) * 8];
    }
    __builtin_amdgcn_s_setprio(1);
    #pragma unroll
    for (int mi = 0; mi < 4; ++mi)
      #pragma unroll
      for (int ni = 0; ni < 2; ++ni) {
        accg[mi][ni] = __builtin_amdgcn_mfma_f32_16x16x32_bf16(a[mi], bgf[ni], accg[mi][ni], 0, 0, 0);
        accu[mi][ni] = __builtin_amdgcn_mfma_f32_16x16x32_bf16(a[mi], buf_[ni], accu[mi][ni], 0, 0, 0);
      }
    __builtin_amdgcn_s_setprio(0);

    pb0 = nb0; pb1 = nb1;
    cur = (cur + 1 >= 3) ? 0 : cur + 1;
  }

  // epilogue: h = silu(g)*u*w -> bf16
  #pragma unroll
  for (int mi = 0; mi < 4; ++mi) {
    #pragma unroll
    for (int r = 0; r < 4; ++r) {
      int row = wm * 64 + mi * 16 + lhi * 4 + r;
      if (row < valid) {
        int grow = row_base + row;
        float wv = wgt[grow];
        size_t base = (size_t)grow * DFF + n0 + wn * 32;
        #pragma unroll
        for (int ni = 0; ni < 2; ++ni) {
          float g = accg[mi][ni][r];
          float u = accu[mi][ni][r];
          float h = (g / (1.f + __expf(-g))) * u * wv;
          hbuf[base + ni * 16 + llo] = f2bf(h);
        }
      }
    }
  }
}

// ---------- 4. down GEMM BM=256 x BN=128: f32 down_w reg-staged in-loop
//             (no dconv, no dbuf), 3-buffer, vmcnt(6), bf16 ybuf ----------
#define BM_B 256
#define BN_B 128
#define NT_B (D_DIM / BN_B)     // 8
#define SLICES_B 4
#define NWT_B (NT_B * SLICES_B) // 32
#define NWG_B (MAXTM2 * NWT_B)  // 768

template <bool USE_YBUF>
__global__ __launch_bounds__(512) void moe_down_f32r(
    const float* __restrict__ down_w,
    const unsigned short* __restrict__ hbuf,
    const int* __restrict__ tok,
    const int* __restrict__ tl2,
    unsigned short* __restrict__ ybuf, float* __restrict__ out_atomic)
{
  constexpr int KS = DFF / SLICES_B;   // 704
  constexpr int KT = KS / BK;          // 22

  const int bid = blockIdx.x;
  const int ntm = tl2[TL_N];
  const int nwork = ntm * NWT_B;
  if (bid >= nwork) return;
  const int w = xcd_chunk(bid, nwork);
  const int tile = w / NWT_B;
  const int rr   = w % NWT_B;
  const int nt = rr & 7;
  const int sl = rr >> 3;
  const int row_base = tl2[TL_BASE + tile];
  const int valid    = tl2[TL_VAL  + tile];
  const int e        = tl2[TL_EXP  + tile];
  const int n0 = nt * BN_B;
  const int kbeg = sl * KS;

  __shared__ __align__(16) unsigned short Alds[3][BM_B * BK]; // 3 x 16KB
  __shared__ __align__(16) unsigned short Blds[3][BN_B * BK]; // 3 x 8KB -> 72KB

  const int tid = threadIdx.x, lane = tid & 63, wid = tid >> 6;
  const int wm = wid >> 1, wn = wid & 1;   // 4x2 waves, wave tile 64x64
  const int lhi = lane >> 4, llo = lane & 15;

  f32x4 acc[4][4];
  #pragma unroll
  for (int i = 0; i < 4; ++i)
    #pragma unroll
    for (int j = 0; j < 4; ++j) acc[i][j] = (f32x4){0.f, 0.f, 0.f, 0.f};

  const int ar0 = tid >> 2, ag = tid & 3;
  const int ar1 = ar0 + 128;
  const size_t a_src0 = (size_t)(row_base + min(ar0, valid - 1)) * DFF + SWZ(ar0, ag) * 8;
  const size_t a_src1 = (size_t)(row_base + min(ar1, valid - 1)) * DFF + SWZ(ar1, ag) * 8;

  // B: f32 down_w, 1 granule (8 f32) per thread per K-step; rows 0..127
  const int brr = tid >> 2, bgg = tid & 3;
  const float* bsrc = down_w + ((size_t)e * D_DIM + n0 + brr) * DFF + bgg * 8 + kbeg;
  const int bws = brr * BK + SWZ(brr, bgg) * 8;

  // ---- prologue ----
  {
    float4 c0 = *(const float4*)(bsrc);
    float4 c1 = *(const float4*)(bsrc + 4);
    *(ushort8*)&Blds[0][bws] = pack_bf16x8(c0, c1);
  }
  float4 pb0 = *(const float4*)(bsrc + BK);
  float4 pb1 = *(const float4*)(bsrc + BK + 4);
  lds_cp16(hbuf + a_src0 + kbeg, &Alds[0][tid * 8]);
  lds_cp16(hbuf + a_src1 + kbeg, &Alds[0][(tid + 512) * 8]);
  lds_cp16(hbuf + a_src0 + kbeg + BK, &Alds[1][tid * 8]);
  lds_cp16(hbuf + a_src1 + kbeg + BK, &Alds[1][(tid + 512) * 8]);
  asm volatile("s_waitcnt vmcnt(0) lgkmcnt(0)" ::: "memory");
  __builtin_amdgcn_s_barrier();

  int cur = 0;
  for (int t = 0; t < KT; ++t) {
    const int nxt = (cur + 1 >= 3) ? cur - 2 : cur + 1;
    const int nb  = (cur + 2 >= 3) ? cur - 1 : cur + 2;
    const int kn2 = (t + 2 < KT) ? (t + 2) * BK : 0;

    // pre-barrier: B(t+2) f32 -> regs only
    float4 nb0 = *(const float4*)(bsrc + kn2);
    float4 nb1 = *(const float4*)(bsrc + kn2 + 4);

    asm volatile("s_waitcnt vmcnt(6) lgkmcnt(0)" ::: "memory");
    __builtin_amdgcn_s_barrier();

    // post-barrier staging
    lds_cp16(hbuf + a_src0 + kbeg + kn2, &Alds[nb][tid * 8]);
    lds_cp16(hbuf + a_src1 + kbeg + kn2, &Alds[nb][(tid + 512) * 8]);
    *(ushort8*)&Blds[nxt][bws] = pack_bf16x8(pb0, pb1);

    bf16x8 a[4], b[4];
    #pragma unroll
    for (int mi = 0; mi < 4; ++mi) {
      int row = wm * 64 + mi * 16 + llo;
      a[mi] = *(const bf16x8*)&Alds[cur][row * BK + SWZ(row, lhi) * 8];
    }
    #pragma unroll
    for (int ni = 0; ni < 4; ++ni) {
      int row = wn * 64 + ni * 16 + llo;
      b[ni] = *(const bf16x8*)&Blds[cur][row * BK + SWZ(row, lhi) * 8];
    }
    __builtin_amdgcn_s_setprio(1);
    #pragma unroll
    for (int mi = 0; mi < 4; ++mi)
      #pragma unroll
      for (int ni = 0; ni < 4; ++ni)
        acc[mi][ni] = __builtin_amdgcn_mfma_f32_16x16x32_bf16(a[mi], b[ni], acc[mi][ni], 0, 0, 0);
    __builtin_amdgcn_s_setprio(0);

    pb0 = nb0; pb1 = nb1;
    cur = (cur + 1 >= 3) ? 0 : cur + 1;
  }

  #pragma unroll
  for (int mi = 0; mi < 4; ++mi) {
    #pragma unroll
    for (int r = 0; r < 4; ++r) {
      int row = wm * 64 + mi * 16 + lhi * 4 + r;
      if (row < valid) {
        if (USE_YBUF) {
          unsigned short* yp = ybuf + ((size_t)sl * NROWS + row_base + row) * D_DIM + n0 + wn * 64;
          #pragma unroll
          for (int ni = 0; ni < 4; ++ni) yp[ni * 16 + llo] = f2bf(acc[mi][ni][r]);
        } else {
          int tk = tok[row_base + row];
          float* op = out_atomic + (size_t)tk * D_DIM + n0 + wn * 64;
          #pragma unroll
          for (int ni = 0; ni < 4; ++ni) atomicAdd(op + ni * 16 + llo, acc[mi][ni][r]);
        }
      }
    }
  }
}

// ---------- 5. combine (bf16 partials -> f32 out) ----------
__global__ __launch_bounds__(256) void combine_kernel(
    const unsigned short* __restrict__ ybuf, const int* __restrict__ rowmap,
    float* __restrict__ out)
{
  const int t = blockIdx.x;
  const int d = threadIdx.x * 4;
  const int r0 = rowmap[t * 2], r1 = rowmap[t * 2 + 1];
  float s0 = 0.f, s1 = 0.f, s2 = 0.f, s3 = 0.f;
  #pragma unroll
  for (int sl = 0; sl < SLICES_B; ++sl) {
    ushort4 a = *(const ushort4*)(ybuf + ((size_t)sl * NROWS + r0) * D_DIM + d);
    ushort4 b = *(const ushort4*)(ybuf + ((size_t)sl * NROWS + r1) * D_DIM + d);
    s0 += bf2f(a.x) + bf2f(b.x);
    s1 += bf2f(a.y) + bf2f(b.y);
    s2 += bf2f(a.z) + bf2f(b.z);
    s3 += bf2f(a.w) + bf2f(b.w);
  }
  float4 s = {s0, s1, s2, s3};
  *(float4*)(out + (size_t)t * D_DIM + d) = s;
}

// ---------- launch ----------
extern "C" void kernel_launch(void* const* d_in, const int* in_sizes, int n_in,
                              void* d_out, int out_size, void* d_ws, size_t ws_size,
                              hipStream_t stream) {
  const float* x      = (const float*)d_in[0];
  const float* topk_w = (const float*)d_in[1];
  const float* gate_w = (const float*)d_in[2];
  const float* up_w   = (const float*)d_in[3];
  const float* down_w = (const float*)d_in[4];
  const int*   ids    = (const int*)d_in[5];
  float* out = (float*)d_out;

  char* ws = (char*)d_ws;
  int*   cnt    = (int*)(ws + 0);
  int*   off    = (int*)(ws + 32);
  int*   tok    = (int*)(ws + 64);
  float* wgt    = (float*)(ws + 64 + NROWS * 4);
  int*   rowmap = (int*)(ws + 64 + NROWS * 8);
  int*   tl2    = (int*)(ws + 50688);

  const size_t XG_OFF = 65536;
  const size_t XG_SZ  = (size_t)NROWS * D_DIM * 2;            // 8 MB
  const size_t HB_OFF = XG_OFF + XG_SZ;
  const size_t HB_SZ  = (size_t)NROWS * DFF * 2;              // 23.07 MB
  const size_t YB_OFF = HB_OFF + HB_SZ;
  const size_t YB_SZ  = (size_t)SLICES_B * NROWS * D_DIM * 2; // 33.6 MB (bf16)

  unsigned short* xg   = (unsigned short*)(ws + XG_OFF);
  unsigned short* hbuf = (unsigned short*)(ws + HB_OFF);
  unsigned short* ybuf = (unsigned short*)(ws + YB_OFF);

  routing_kernel<<<1, 512, 0, stream>>>(ids, topk_w, cnt, off, tok, wgt, rowmap, tl2);
  gather_x_kernel<<<NROWS, 256, 0, stream>>>(x, tok, xg);
  moe_gateup_f32r<<<NWG_A, 512, 0, stream>>>(gate_w, up_w, xg, wgt, tl2, hbuf);

  if (ws_size >= YB_OFF + YB_SZ) {
    moe_down_f32r<true><<<NWG_B, 512, 0, stream>>>(down_w, hbuf, tok, tl2, ybuf, nullptr);
    combine_kernel<<<T_TOK, 256, 0, stream>>>(ybuf, rowmap, out);
  } else {
    hipMemsetAsync(d_out, 0, (size_t)out_size * sizeof(float), stream);
    moe_down_f32r<false><<<NWG_B, 512, 0, stream>>>(down_w, hbuf, tok, tl2, nullptr, out);
  }
}